// Round 1
// baseline (346.461 us; speedup 1.0000x reference)
//
#include <hip/hip_runtime.h>
#include <math.h>

#define B_SZ 4
#define LQ_SZ 2048
#define C_SZ 256
#define NH_SZ 8
#define NL_SZ 4
#define NP_SZ 8
#define HD_SZ 32
#define LV_SZ 21760
#define NQ_SZ (B_SZ * LQ_SZ)   // 8192
#define MV_SZ (B_SZ * LV_SZ)   // 87040

// ---------------------------------------------------------------------------
// Generic f32 GEMM: Cout[M,256] = A[M,256] @ W[256,256] + bias
// BM=128, BN=128, BK=16, 256 threads, 8x8 micro-tile per thread.
// grid = (M/128, 2)
// ---------------------------------------------------------------------------
__global__ __launch_bounds__(256, 2) void gemm256_f32(
    const float* __restrict__ A, const float* __restrict__ W,
    const float* __restrict__ bias, float* __restrict__ Cout) {
  __shared__ float As[16][128];
  __shared__ float Bs[16][128];
  const int tid = threadIdx.x;
  const long bm = (long)blockIdx.x * 128;
  const int bn = blockIdx.y * 128;
  const int tr = tid >> 4, tc = tid & 15;
  const int arow = tid >> 1, akq = (tid & 1) * 8;
  const int brow = tid >> 4, bnq = (tid & 15) * 8;

  float acc[8][8];
#pragma unroll
  for (int i = 0; i < 8; ++i)
#pragma unroll
    for (int j = 0; j < 8; ++j) acc[i][j] = 0.f;

  for (int k0 = 0; k0 < 256; k0 += 16) {
    float4 a0 = *(const float4*)(A + (bm + arow) * 256 + k0 + akq);
    float4 a1 = *(const float4*)(A + (bm + arow) * 256 + k0 + akq + 4);
    float4 b0 = *(const float4*)(W + (long)(k0 + brow) * 256 + bn + bnq);
    float4 b1 = *(const float4*)(W + (long)(k0 + brow) * 256 + bn + bnq + 4);
    As[akq + 0][arow] = a0.x;
    As[akq + 1][arow] = a0.y;
    As[akq + 2][arow] = a0.z;
    As[akq + 3][arow] = a0.w;
    As[akq + 4][arow] = a1.x;
    As[akq + 5][arow] = a1.y;
    As[akq + 6][arow] = a1.z;
    As[akq + 7][arow] = a1.w;
    *(float4*)&Bs[brow][bnq] = b0;
    *(float4*)&Bs[brow][bnq + 4] = b1;
    __syncthreads();
#pragma unroll
    for (int k = 0; k < 16; ++k) {
      float4 x0 = *(const float4*)&As[k][tr * 8];
      float4 x1 = *(const float4*)&As[k][tr * 8 + 4];
      float4 y0 = *(const float4*)&Bs[k][tc * 8];
      float4 y1 = *(const float4*)&Bs[k][tc * 8 + 4];
      float ar[8] = {x0.x, x0.y, x0.z, x0.w, x1.x, x1.y, x1.z, x1.w};
      float br[8] = {y0.x, y0.y, y0.z, y0.w, y1.x, y1.y, y1.z, y1.w};
#pragma unroll
      for (int i = 0; i < 8; ++i)
#pragma unroll
        for (int j = 0; j < 8; ++j) acc[i][j] = fmaf(ar[i], br[j], acc[i][j]);
    }
    __syncthreads();
  }

  float bj[8];
#pragma unroll
  for (int j = 0; j < 8; ++j) bj[j] = bias[bn + tc * 8 + j];
#pragma unroll
  for (int i = 0; i < 8; ++i) {
    float* dst = Cout + (bm + tr * 8 + i) * 256 + bn + tc * 8;
    float4 s0 = {acc[i][0] + bj[0], acc[i][1] + bj[1], acc[i][2] + bj[2],
                 acc[i][3] + bj[3]};
    float4 s1 = {acc[i][4] + bj[4], acc[i][5] + bj[5], acc[i][6] + bj[6],
                 acc[i][7] + bj[7]};
    *(float4*)dst = s0;
    *(float4*)(dst + 4) = s1;
  }
}

// ---------------------------------------------------------------------------
// Query-side projections, fused: offsets (two-GEMM sum) -> sampling grid,
// attention logits -> softmax weights. One block = 16 queries, 256 threads.
// grid_out: (NQ, NH, NL, NP, 2)   aw_out: (NQ, NH, NL, NP)
// ---------------------------------------------------------------------------
__global__ __launch_bounds__(256, 2) void qproj_kernel(
    const float* __restrict__ query, const float* __restrict__ refpts,
    const float* __restrict__ W_off, const float* __restrict__ b_off,
    const float* __restrict__ W_attn, const float* __restrict__ b_attn,
    const float* __restrict__ Wa1, const float* __restrict__ ba1,
    const float* __restrict__ Wa2, const float* __restrict__ ba2,
    float* __restrict__ grid_out, float* __restrict__ aw_out) {
  __shared__ float qs[16][256];
  __shared__ float hs[16][128];
  const int tid = threadIdx.x;
  const long q0 = (long)blockIdx.x * 16;

  // stage 16 query rows in LDS
  {
    const int row = tid >> 4, cq = (tid & 15) * 16;
    const float* src = query + (q0 + row) * 256 + cq;
#pragma unroll
    for (int i = 0; i < 4; ++i)
      *(float4*)&qs[row][cq + 4 * i] = *(const float4*)(src + 4 * i);
  }
  __syncthreads();

  // hid = relu(q @ Wa1 + ba1): 16 x 128, 8 outputs/thread
  {
    const int j = tid & 127, qh = (tid >> 7) * 8;
    float acc[8];
#pragma unroll
    for (int i = 0; i < 8; ++i) acc[i] = 0.f;
    for (int k0 = 0; k0 < 256; k0 += 4) {
      float w0 = Wa1[(k0 + 0) * 128 + j];
      float w1 = Wa1[(k0 + 1) * 128 + j];
      float w2 = Wa1[(k0 + 2) * 128 + j];
      float w3 = Wa1[(k0 + 3) * 128 + j];
#pragma unroll
      for (int i = 0; i < 8; ++i) {
        float4 qv = *(const float4*)&qs[qh + i][k0];
        acc[i] = fmaf(qv.x, w0, acc[i]);
        acc[i] = fmaf(qv.y, w1, acc[i]);
        acc[i] = fmaf(qv.z, w2, acc[i]);
        acc[i] = fmaf(qv.w, w3, acc[i]);
      }
    }
    const float bb = ba1[j];
#pragma unroll
    for (int i = 0; i < 8; ++i) hs[qh + i][j] = fmaxf(acc[i] + bb, 0.f);
  }
  __syncthreads();

  // off = q@W_off + b_off + 0.1*(hid@Wa2 + ba2) -> grid. o0=tid, o1=tid+256.
  {
    float acc0[16], acc1[16];
#pragma unroll
    for (int q = 0; q < 16; ++q) { acc0[q] = 0.f; acc1[q] = 0.f; }
    for (int k0 = 0; k0 < 256; k0 += 4) {
      float w00 = W_off[(k0 + 0) * 512 + tid];
      float w01 = W_off[(k0 + 1) * 512 + tid];
      float w02 = W_off[(k0 + 2) * 512 + tid];
      float w03 = W_off[(k0 + 3) * 512 + tid];
      float w10 = W_off[(k0 + 0) * 512 + tid + 256];
      float w11 = W_off[(k0 + 1) * 512 + tid + 256];
      float w12 = W_off[(k0 + 2) * 512 + tid + 256];
      float w13 = W_off[(k0 + 3) * 512 + tid + 256];
#pragma unroll
      for (int q = 0; q < 16; ++q) {
        float4 qv = *(const float4*)&qs[q][k0];
        acc0[q] = fmaf(qv.x, w00, acc0[q]);
        acc0[q] = fmaf(qv.y, w01, acc0[q]);
        acc0[q] = fmaf(qv.z, w02, acc0[q]);
        acc0[q] = fmaf(qv.w, w03, acc0[q]);
        acc1[q] = fmaf(qv.x, w10, acc1[q]);
        acc1[q] = fmaf(qv.y, w11, acc1[q]);
        acc1[q] = fmaf(qv.z, w12, acc1[q]);
        acc1[q] = fmaf(qv.w, w13, acc1[q]);
      }
    }
    for (int k0 = 0; k0 < 128; k0 += 4) {
      float w00 = 0.1f * Wa2[(k0 + 0) * 512 + tid];
      float w01 = 0.1f * Wa2[(k0 + 1) * 512 + tid];
      float w02 = 0.1f * Wa2[(k0 + 2) * 512 + tid];
      float w03 = 0.1f * Wa2[(k0 + 3) * 512 + tid];
      float w10 = 0.1f * Wa2[(k0 + 0) * 512 + tid + 256];
      float w11 = 0.1f * Wa2[(k0 + 1) * 512 + tid + 256];
      float w12 = 0.1f * Wa2[(k0 + 2) * 512 + tid + 256];
      float w13 = 0.1f * Wa2[(k0 + 3) * 512 + tid + 256];
#pragma unroll
      for (int q = 0; q < 16; ++q) {
        float4 hv = *(const float4*)&hs[q][k0];
        acc0[q] = fmaf(hv.x, w00, acc0[q]);
        acc0[q] = fmaf(hv.y, w01, acc0[q]);
        acc0[q] = fmaf(hv.z, w02, acc0[q]);
        acc0[q] = fmaf(hv.w, w03, acc0[q]);
        acc1[q] = fmaf(hv.x, w10, acc1[q]);
        acc1[q] = fmaf(hv.y, w11, acc1[q]);
        acc1[q] = fmaf(hv.z, w12, acc1[q]);
        acc1[q] = fmaf(hv.w, w13, acc1[q]);
      }
    }
    const float bias0 = b_off[tid] + 0.1f * ba2[tid];
    const float bias1 = b_off[tid + 256] + 0.1f * ba2[tid + 256];
#pragma unroll
    for (int half = 0; half < 2; ++half) {
      const int o = tid + half * 256;
      const int l = (o >> 4) & 3;
      const int c = o & 1;
      const float rnorm = 1.f / (float)(128 >> l);  // H==W per level
      const float bia = half ? bias1 : bias0;
#pragma unroll
      for (int q = 0; q < 16; ++q) {
        float offv = (half ? acc1[q] : acc0[q]) + bia;
        float ref = refpts[(q0 + q) * 8 + l * 2 + c];
        grid_out[(q0 + q) * 512 + o] = (ref + offv * rnorm) * 2.f - 1.f;
      }
    }
  }

  // attention logits + per-head softmax over NL*NP=32 (32-lane subgroups)
  {
    float acc[16];
#pragma unroll
    for (int q = 0; q < 16; ++q) acc[q] = 0.f;
    for (int k0 = 0; k0 < 256; k0 += 4) {
      float w0 = W_attn[(k0 + 0) * 256 + tid];
      float w1 = W_attn[(k0 + 1) * 256 + tid];
      float w2 = W_attn[(k0 + 2) * 256 + tid];
      float w3 = W_attn[(k0 + 3) * 256 + tid];
#pragma unroll
      for (int q = 0; q < 16; ++q) {
        float4 qv = *(const float4*)&qs[q][k0];
        acc[q] = fmaf(qv.x, w0, acc[q]);
        acc[q] = fmaf(qv.y, w1, acc[q]);
        acc[q] = fmaf(qv.z, w2, acc[q]);
        acc[q] = fmaf(qv.w, w3, acc[q]);
      }
    }
    const float bb = b_attn[tid];
#pragma unroll
    for (int q = 0; q < 16; ++q) {
      float vv = acc[q] + bb;
      float m = vv;
#pragma unroll
      for (int mask = 16; mask > 0; mask >>= 1)
        m = fmaxf(m, __shfl_xor(m, mask));
      float e = __expf(vv - m);
      float s = e;
#pragma unroll
      for (int mask = 16; mask > 0; mask >>= 1) s += __shfl_xor(s, mask);
      aw_out[(q0 + q) * 256 + tid] = e / s;
    }
  }
}

// ---------------------------------------------------------------------------
// Bilinear sampling + attention-weighted accumulation.
// One block per query (b,q); 256 threads = 8 heads x 32 channels.
// v layout: (B, Lv, NH, HD) -> row of 32 floats contiguous per (b,loc,h).
// ---------------------------------------------------------------------------
__global__ __launch_bounds__(256) void sample_kernel(
    const float* __restrict__ v, const float* __restrict__ grid,
    const float* __restrict__ aw, float* __restrict__ acc_out) {
  const long qi = blockIdx.x;     // 0..8191
  const int b = (int)(qi >> 11);  // / LQ
  const int tid = threadIdx.x;
  const int h = tid >> 5, d = tid & 31;

  __shared__ float gs[512];
  __shared__ float aws[256];
  if (tid < 128) {
    ((float4*)gs)[tid] = ((const float4*)(grid + qi * 512))[tid];
  } else if (tid < 192) {
    ((float4*)aws)[tid - 128] = ((const float4*)(aw + qi * 256))[tid - 128];
  }
  __syncthreads();

  constexpr int starts[4] = {0, 16384, 20480, 21504};
  float acc = 0.f;
  const float* vb = v + (long)b * LV_SZ * 256 + h * 32 + d;
#pragma unroll
  for (int l = 0; l < 4; ++l) {
    const int HW = 128 >> l;
    const float fHW = (float)HW;
    const float* vl = vb + (long)starts[l] * 256;
#pragma unroll
    for (int p = 0; p < 8; ++p) {
      const int gidx = h * 64 + l * 16 + p * 2;
      const float gx = gs[gidx], gy = gs[gidx + 1];
      const float w = aws[h * 32 + l * 8 + p];
      const float x = ((gx + 1.f) * fHW - 1.f) * 0.5f;
      const float y = ((gy + 1.f) * fHW - 1.f) * 0.5f;
      const float x0f = floorf(x), y0f = floorf(y);
      const float lx = x - x0f, ly = y - y0f;
      const int ix0 = (int)x0f, iy0 = (int)y0f;
      const int ix1 = ix0 + 1, iy1 = iy0 + 1;
      const float vx0 = (ix0 >= 0 && ix0 < HW) ? 1.f : 0.f;
      const float vx1 = (ix1 >= 0 && ix1 < HW) ? 1.f : 0.f;
      const float vy0 = (iy0 >= 0 && iy0 < HW) ? 1.f : 0.f;
      const float vy1 = (iy1 >= 0 && iy1 < HW) ? 1.f : 0.f;
      const int cx0 = min(max(ix0, 0), HW - 1);
      const int cx1 = min(max(ix1, 0), HW - 1);
      const int cy0 = min(max(iy0, 0), HW - 1);
      const int cy1 = min(max(iy1, 0), HW - 1);
      const float w00 = (1.f - lx) * (1.f - ly) * vx0 * vy0 * w;
      const float w10 = lx * (1.f - ly) * vx1 * vy0 * w;
      const float w01 = (1.f - lx) * ly * vx0 * vy1 * w;
      const float w11 = lx * ly * vx1 * vy1 * w;
      const float* r0 = vl + (long)(cy0 * HW) * 256;
      const float* r1 = vl + (long)(cy1 * HW) * 256;
      const float v00 = r0[(long)cx0 * 256];
      const float v10 = r0[(long)cx1 * 256];
      const float v01 = r1[(long)cx0 * 256];
      const float v11 = r1[(long)cx1 * 256];
      acc = fmaf(v00, w00, acc);
      acc = fmaf(v10, w10, acc);
      acc = fmaf(v01, w01, acc);
      acc = fmaf(v11, w11, acc);
    }
  }
  acc_out[qi * 256 + tid] = acc;
}

// ---------------------------------------------------------------------------
extern "C" void kernel_launch(void* const* d_in, const int* in_sizes, int n_in,
                              void* d_out, int out_size, void* d_ws,
                              size_t ws_size, hipStream_t stream) {
  const float* query  = (const float*)d_in[0];
  const float* refpts = (const float*)d_in[1];
  const float* value  = (const float*)d_in[2];
  const float* W_off  = (const float*)d_in[5];
  const float* b_off  = (const float*)d_in[6];
  const float* W_attn = (const float*)d_in[7];
  const float* b_attn = (const float*)d_in[8];
  const float* Wa1    = (const float*)d_in[9];
  const float* ba1    = (const float*)d_in[10];
  const float* Wa2    = (const float*)d_in[11];
  const float* ba2    = (const float*)d_in[12];
  const float* Wv     = (const float*)d_in[13];
  const float* bv     = (const float*)d_in[14];
  const float* Wo     = (const float*)d_in[15];
  const float* bo     = (const float*)d_in[16];
  float* out = (float*)d_out;

  char* ws = (char*)d_ws;
  float* v_ws    = (float*)ws;                                   // 89,128,960 B
  float* grid_ws = (float*)(ws + 89128960);                      // 16,777,216 B
  float* aw_ws   = (float*)(ws + 89128960 + 16777216);           //  8,388,608 B
  float* acc_ws  = (float*)(ws + 89128960 + 16777216 + 8388608); //  8,388,608 B

  // 1) v = value @ Wv + bv   (M = 87040)
  gemm256_f32<<<dim3(MV_SZ / 128, 2), 256, 0, stream>>>(value, Wv, bv, v_ws);
  // 2) grids + attention weights
  qproj_kernel<<<NQ_SZ / 16, 256, 0, stream>>>(query, refpts, W_off, b_off,
                                               W_attn, b_attn, Wa1, ba1, Wa2,
                                               ba2, grid_ws, aw_ws);
  // 3) bilinear sampling + weighted accumulation
  sample_kernel<<<NQ_SZ, 256, 0, stream>>>(v_ws, grid_ws, aw_ws, acc_ws);
  // 4) out = acc @ Wo + bo   (M = 8192)
  gemm256_f32<<<dim3(NQ_SZ / 128, 2), 256, 0, stream>>>(acc_ws, Wo, bo, out);
}

// Round 2
// 244.997 us; speedup vs baseline: 1.4141x; 1.4141x over previous
//
#include <hip/hip_runtime.h>
#include <math.h>

#define B_SZ 4
#define LQ_SZ 2048
#define C_SZ 256
#define NH_SZ 8
#define NL_SZ 4
#define NP_SZ 8
#define HD_SZ 32
#define LV_SZ 21760
#define NQ_SZ (B_SZ * LQ_SZ)   // 8192
#define MV_SZ (B_SZ * LV_SZ)   // 87040

typedef __attribute__((ext_vector_type(8))) short bf16x8;
typedef __attribute__((ext_vector_type(8))) unsigned short ushort8;
typedef __attribute__((ext_vector_type(4))) float f32x4;

__device__ __forceinline__ float bf2f(unsigned short u) {
  union { float f; unsigned v; } x;
  x.v = ((unsigned)u) << 16;
  return x.f;
}
__device__ __forceinline__ unsigned short f2bf(float f) {
  union { float f; unsigned v; } x;
  x.f = f;
  unsigned r = x.v + 0x7fffu + ((x.v >> 16) & 1u);
  return (unsigned short)(r >> 16);
}

// ---------------------------------------------------------------------------
// One-off: Wt[n][k] = bf16(W[k][n])  (256x256)
// ---------------------------------------------------------------------------
__global__ void convert_wt(const float* __restrict__ W,
                           unsigned short* __restrict__ Wt) {
  const int n = blockIdx.x, k = threadIdx.x;
  Wt[n * 256 + k] = f2bf(W[k * 256 + n]);
}

// ---------------------------------------------------------------------------
// MFMA GEMM: C[M,256] = A[M,256](f32) @ W[256,256] + bias
// W given pre-transposed bf16: Wt[n][k]. BM=128, BN=256 (full), BK=32.
// 512 threads = 8 waves (2 row x 4 col), each wave 64x64 = 4x4 fragments.
// OUT_BF16: 1 -> store bf16 (ushort), 0 -> store f32.
// ---------------------------------------------------------------------------
#define AS_STRIDE 40  // ushorts per LDS row (80 B = 5*16B -> 2-way alias only)

template <int OUT_BF16>
__global__ __launch_bounds__(512, 1) void gemm_mfma(
    const float* __restrict__ A, const unsigned short* __restrict__ Wt,
    const float* __restrict__ bias, void* __restrict__ Cout) {
  __shared__ unsigned short As[2][128 * AS_STRIDE];
  const int tid = threadIdx.x;
  const long bm = (long)blockIdx.x * 128;
  const int lane = tid & 63;
  const int wid = tid >> 6;
  const int wr = wid >> 2;    // 0..1
  const int wc = wid & 3;     // 0..3
  const int rowg = (lane >> 4);      // 0..3
  const int rowc = lane & 15;        // 0..15

  // staging decomposition: thread -> (row, k-chunk)
  const int srow = tid >> 2;          // 0..127
  const int skc = (tid & 3) * 8;      // 0,8,16,24

  f32x4 acc[4][4];
#pragma unroll
  for (int m = 0; m < 4; ++m)
#pragma unroll
    for (int n = 0; n < 4; ++n) acc[m][n] = (f32x4){0.f, 0.f, 0.f, 0.f};

  const float* srcbase = A + (bm + srow) * 256 + skc;

  // prologue: stage k-tile 0 into buf 0
  {
    float4 f0 = *(const float4*)(srcbase + 0);
    float4 f1 = *(const float4*)(srcbase + 4);
    ushort8 u;
    u[0] = f2bf(f0.x); u[1] = f2bf(f0.y); u[2] = f2bf(f0.z); u[3] = f2bf(f0.w);
    u[4] = f2bf(f1.x); u[5] = f2bf(f1.y); u[6] = f2bf(f1.z); u[7] = f2bf(f1.w);
    *(ushort8*)&As[0][srow * AS_STRIDE + skc] = u;
  }
  __syncthreads();

  int cur = 0;
#pragma unroll
  for (int ks = 0; ks < 8; ++ks) {
    float4 pf0, pf1;
    if (ks < 7) {
      pf0 = *(const float4*)(srcbase + (ks + 1) * 32 + 0);
      pf1 = *(const float4*)(srcbase + (ks + 1) * 32 + 4);
    }
    // B fragments straight from L2-resident transposed weights
    bf16x8 bfrag[4];
#pragma unroll
    for (int n = 0; n < 4; ++n) {
      const unsigned short* wp =
          Wt + (long)(wc * 64 + n * 16 + rowc) * 256 + ks * 32 + rowg * 8;
      bfrag[n] = *(const bf16x8*)wp;
    }
    // A fragments from LDS
    bf16x8 afrag[4];
#pragma unroll
    for (int m = 0; m < 4; ++m) {
      const int r = wr * 64 + m * 16 + rowc;
      afrag[m] = *(const bf16x8*)&As[cur][r * AS_STRIDE + rowg * 8];
    }
#pragma unroll
    for (int m = 0; m < 4; ++m)
#pragma unroll
      for (int n = 0; n < 4; ++n)
        acc[m][n] = __builtin_amdgcn_mfma_f32_16x16x32_bf16(
            afrag[m], bfrag[n], acc[m][n], 0, 0, 0);

    if (ks < 7) {
      ushort8 u;
      u[0] = f2bf(pf0.x); u[1] = f2bf(pf0.y); u[2] = f2bf(pf0.z); u[3] = f2bf(pf0.w);
      u[4] = f2bf(pf1.x); u[5] = f2bf(pf1.y); u[6] = f2bf(pf1.z); u[7] = f2bf(pf1.w);
      *(ushort8*)&As[cur ^ 1][srow * AS_STRIDE + skc] = u;
    }
    __syncthreads();
    cur ^= 1;
  }

  // epilogue
#pragma unroll
  for (int m = 0; m < 4; ++m) {
#pragma unroll
    for (int n = 0; n < 4; ++n) {
      const int col = wc * 64 + n * 16 + rowc;
      const float bb = bias[col];
#pragma unroll
      for (int j = 0; j < 4; ++j) {
        const long row = bm + wr * 64 + m * 16 + rowg * 4 + j;
        const float val = acc[m][n][j] + bb;
        if (OUT_BF16)
          ((unsigned short*)Cout)[row * 256 + col] = f2bf(val);
        else
          ((float*)Cout)[row * 256 + col] = val;
      }
    }
  }
}

// ---------------------------------------------------------------------------
// Query-side projections, fused (unchanged from round 1).
// ---------------------------------------------------------------------------
__global__ __launch_bounds__(256, 2) void qproj_kernel(
    const float* __restrict__ query, const float* __restrict__ refpts,
    const float* __restrict__ W_off, const float* __restrict__ b_off,
    const float* __restrict__ W_attn, const float* __restrict__ b_attn,
    const float* __restrict__ Wa1, const float* __restrict__ ba1,
    const float* __restrict__ Wa2, const float* __restrict__ ba2,
    float* __restrict__ grid_out, float* __restrict__ aw_out) {
  __shared__ float qs[16][256];
  __shared__ float hs[16][128];
  const int tid = threadIdx.x;
  const long q0 = (long)blockIdx.x * 16;

  {
    const int row = tid >> 4, cq = (tid & 15) * 16;
    const float* src = query + (q0 + row) * 256 + cq;
#pragma unroll
    for (int i = 0; i < 4; ++i)
      *(float4*)&qs[row][cq + 4 * i] = *(const float4*)(src + 4 * i);
  }
  __syncthreads();

  {
    const int j = tid & 127, qh = (tid >> 7) * 8;
    float acc[8];
#pragma unroll
    for (int i = 0; i < 8; ++i) acc[i] = 0.f;
    for (int k0 = 0; k0 < 256; k0 += 4) {
      float w0 = Wa1[(k0 + 0) * 128 + j];
      float w1 = Wa1[(k0 + 1) * 128 + j];
      float w2 = Wa1[(k0 + 2) * 128 + j];
      float w3 = Wa1[(k0 + 3) * 128 + j];
#pragma unroll
      for (int i = 0; i < 8; ++i) {
        float4 qv = *(const float4*)&qs[qh + i][k0];
        acc[i] = fmaf(qv.x, w0, acc[i]);
        acc[i] = fmaf(qv.y, w1, acc[i]);
        acc[i] = fmaf(qv.z, w2, acc[i]);
        acc[i] = fmaf(qv.w, w3, acc[i]);
      }
    }
    const float bb = ba1[j];
#pragma unroll
    for (int i = 0; i < 8; ++i) hs[qh + i][j] = fmaxf(acc[i] + bb, 0.f);
  }
  __syncthreads();

  {
    float acc0[16], acc1[16];
#pragma unroll
    for (int q = 0; q < 16; ++q) { acc0[q] = 0.f; acc1[q] = 0.f; }
    for (int k0 = 0; k0 < 256; k0 += 4) {
      float w00 = W_off[(k0 + 0) * 512 + tid];
      float w01 = W_off[(k0 + 1) * 512 + tid];
      float w02 = W_off[(k0 + 2) * 512 + tid];
      float w03 = W_off[(k0 + 3) * 512 + tid];
      float w10 = W_off[(k0 + 0) * 512 + tid + 256];
      float w11 = W_off[(k0 + 1) * 512 + tid + 256];
      float w12 = W_off[(k0 + 2) * 512 + tid + 256];
      float w13 = W_off[(k0 + 3) * 512 + tid + 256];
#pragma unroll
      for (int q = 0; q < 16; ++q) {
        float4 qv = *(const float4*)&qs[q][k0];
        acc0[q] = fmaf(qv.x, w00, acc0[q]);
        acc0[q] = fmaf(qv.y, w01, acc0[q]);
        acc0[q] = fmaf(qv.z, w02, acc0[q]);
        acc0[q] = fmaf(qv.w, w03, acc0[q]);
        acc1[q] = fmaf(qv.x, w10, acc1[q]);
        acc1[q] = fmaf(qv.y, w11, acc1[q]);
        acc1[q] = fmaf(qv.z, w12, acc1[q]);
        acc1[q] = fmaf(qv.w, w13, acc1[q]);
      }
    }
    for (int k0 = 0; k0 < 128; k0 += 4) {
      float w00 = 0.1f * Wa2[(k0 + 0) * 512 + tid];
      float w01 = 0.1f * Wa2[(k0 + 1) * 512 + tid];
      float w02 = 0.1f * Wa2[(k0 + 2) * 512 + tid];
      float w03 = 0.1f * Wa2[(k0 + 3) * 512 + tid];
      float w10 = 0.1f * Wa2[(k0 + 0) * 512 + tid + 256];
      float w11 = 0.1f * Wa2[(k0 + 1) * 512 + tid + 256];
      float w12 = 0.1f * Wa2[(k0 + 2) * 512 + tid + 256];
      float w13 = 0.1f * Wa2[(k0 + 3) * 512 + tid + 256];
#pragma unroll
      for (int q = 0; q < 16; ++q) {
        float4 hv = *(const float4*)&hs[q][k0];
        acc0[q] = fmaf(hv.x, w00, acc0[q]);
        acc0[q] = fmaf(hv.y, w01, acc0[q]);
        acc0[q] = fmaf(hv.z, w02, acc0[q]);
        acc0[q] = fmaf(hv.w, w03, acc0[q]);
        acc1[q] = fmaf(hv.x, w10, acc1[q]);
        acc1[q] = fmaf(hv.y, w11, acc1[q]);
        acc1[q] = fmaf(hv.z, w12, acc1[q]);
        acc1[q] = fmaf(hv.w, w13, acc1[q]);
      }
    }
    const float bias0 = b_off[tid] + 0.1f * ba2[tid];
    const float bias1 = b_off[tid + 256] + 0.1f * ba2[tid + 256];
#pragma unroll
    for (int half = 0; half < 2; ++half) {
      const int o = tid + half * 256;
      const int l = (o >> 4) & 3;
      const int c = o & 1;
      const float rnorm = 1.f / (float)(128 >> l);
      const float bia = half ? bias1 : bias0;
#pragma unroll
      for (int q = 0; q < 16; ++q) {
        float offv = (half ? acc1[q] : acc0[q]) + bia;
        float ref = refpts[(q0 + q) * 8 + l * 2 + c];
        grid_out[(q0 + q) * 512 + o] = (ref + offv * rnorm) * 2.f - 1.f;
      }
    }
  }

  {
    float acc[16];
#pragma unroll
    for (int q = 0; q < 16; ++q) acc[q] = 0.f;
    for (int k0 = 0; k0 < 256; k0 += 4) {
      float w0 = W_attn[(k0 + 0) * 256 + tid];
      float w1 = W_attn[(k0 + 1) * 256 + tid];
      float w2 = W_attn[(k0 + 2) * 256 + tid];
      float w3 = W_attn[(k0 + 3) * 256 + tid];
#pragma unroll
      for (int q = 0; q < 16; ++q) {
        float4 qv = *(const float4*)&qs[q][k0];
        acc[q] = fmaf(qv.x, w0, acc[q]);
        acc[q] = fmaf(qv.y, w1, acc[q]);
        acc[q] = fmaf(qv.z, w2, acc[q]);
        acc[q] = fmaf(qv.w, w3, acc[q]);
      }
    }
    const float bb = b_attn[tid];
#pragma unroll
    for (int q = 0; q < 16; ++q) {
      float vv = acc[q] + bb;
      float m = vv;
#pragma unroll
      for (int mask = 16; mask > 0; mask >>= 1)
        m = fmaxf(m, __shfl_xor(m, mask));
      float e = __expf(vv - m);
      float s = e;
#pragma unroll
      for (int mask = 16; mask > 0; mask >>= 1) s += __shfl_xor(s, mask);
      aw_out[(q0 + q) * 256 + tid] = e / s;
    }
  }
}

// ---------------------------------------------------------------------------
// Bilinear sampling + attention-weighted accumulation. v is bf16 now.
// One block per query; 256 threads = 8 heads x 32 channels.
// ---------------------------------------------------------------------------
__global__ __launch_bounds__(256) void sample_kernel(
    const unsigned short* __restrict__ v, const float* __restrict__ grid,
    const float* __restrict__ aw, float* __restrict__ acc_out) {
  const long qi = blockIdx.x;
  const int b = (int)(qi >> 11);
  const int tid = threadIdx.x;
  const int h = tid >> 5, d = tid & 31;

  __shared__ float gs[512];
  __shared__ float aws[256];
  if (tid < 128) {
    ((float4*)gs)[tid] = ((const float4*)(grid + qi * 512))[tid];
  } else if (tid < 192) {
    ((float4*)aws)[tid - 128] = ((const float4*)(aw + qi * 256))[tid - 128];
  }
  __syncthreads();

  constexpr int starts[4] = {0, 16384, 20480, 21504};
  float acc = 0.f;
  const unsigned short* vb = v + (long)b * LV_SZ * 256 + h * 32 + d;
#pragma unroll
  for (int l = 0; l < 4; ++l) {
    const int HW = 128 >> l;
    const float fHW = (float)HW;
    const unsigned short* vl = vb + (long)starts[l] * 256;
#pragma unroll
    for (int p = 0; p < 8; ++p) {
      const int gidx = h * 64 + l * 16 + p * 2;
      const float gx = gs[gidx], gy = gs[gidx + 1];
      const float w = aws[h * 32 + l * 8 + p];
      const float x = ((gx + 1.f) * fHW - 1.f) * 0.5f;
      const float y = ((gy + 1.f) * fHW - 1.f) * 0.5f;
      const float x0f = floorf(x), y0f = floorf(y);
      const float lx = x - x0f, ly = y - y0f;
      const int ix0 = (int)x0f, iy0 = (int)y0f;
      const int ix1 = ix0 + 1, iy1 = iy0 + 1;
      const float vx0 = (ix0 >= 0 && ix0 < HW) ? 1.f : 0.f;
      const float vx1 = (ix1 >= 0 && ix1 < HW) ? 1.f : 0.f;
      const float vy0 = (iy0 >= 0 && iy0 < HW) ? 1.f : 0.f;
      const float vy1 = (iy1 >= 0 && iy1 < HW) ? 1.f : 0.f;
      const int cx0 = min(max(ix0, 0), HW - 1);
      const int cx1 = min(max(ix1, 0), HW - 1);
      const int cy0 = min(max(iy0, 0), HW - 1);
      const int cy1 = min(max(iy1, 0), HW - 1);
      const float w00 = (1.f - lx) * (1.f - ly) * vx0 * vy0 * w;
      const float w10 = lx * (1.f - ly) * vx1 * vy0 * w;
      const float w01 = (1.f - lx) * ly * vx0 * vy1 * w;
      const float w11 = lx * ly * vx1 * vy1 * w;
      const unsigned short* r0 = vl + (long)(cy0 * HW) * 256;
      const unsigned short* r1 = vl + (long)(cy1 * HW) * 256;
      const float v00 = bf2f(r0[(long)cx0 * 256]);
      const float v10 = bf2f(r0[(long)cx1 * 256]);
      const float v01 = bf2f(r1[(long)cx0 * 256]);
      const float v11 = bf2f(r1[(long)cx1 * 256]);
      acc = fmaf(v00, w00, acc);
      acc = fmaf(v10, w10, acc);
      acc = fmaf(v01, w01, acc);
      acc = fmaf(v11, w11, acc);
    }
  }
  acc_out[qi * 256 + tid] = acc;
}

// ---------------------------------------------------------------------------
extern "C" void kernel_launch(void* const* d_in, const int* in_sizes, int n_in,
                              void* d_out, int out_size, void* d_ws,
                              size_t ws_size, hipStream_t stream) {
  const float* query  = (const float*)d_in[0];
  const float* refpts = (const float*)d_in[1];
  const float* value  = (const float*)d_in[2];
  const float* W_off  = (const float*)d_in[5];
  const float* b_off  = (const float*)d_in[6];
  const float* W_attn = (const float*)d_in[7];
  const float* b_attn = (const float*)d_in[8];
  const float* Wa1    = (const float*)d_in[9];
  const float* ba1    = (const float*)d_in[10];
  const float* Wa2    = (const float*)d_in[11];
  const float* ba2    = (const float*)d_in[12];
  const float* Wv     = (const float*)d_in[13];
  const float* bv     = (const float*)d_in[14];
  const float* Wo     = (const float*)d_in[15];
  const float* bo     = (const float*)d_in[16];
  float* out = (float*)d_out;

  char* ws = (char*)d_ws;
  unsigned short* v_ws = (unsigned short*)ws;                  // 44,564,480 B
  float* grid_ws = (float*)(ws + 44564480);                    // 16,777,216 B
  float* aw_ws   = (float*)(ws + 61341696);                    //  8,388,608 B
  float* acc_ws  = (float*)(ws + 69730304);                    //  8,388,608 B
  unsigned short* wtv_ws = (unsigned short*)(ws + 78118912);   //    131,072 B
  unsigned short* wto_ws = (unsigned short*)(ws + 78249984);   //    131,072 B

  // 0) transpose+convert weights to bf16
  convert_wt<<<256, 256, 0, stream>>>(Wv, wtv_ws);
  convert_wt<<<256, 256, 0, stream>>>(Wo, wto_ws);
  // 1) v = value @ Wv + bv  (bf16 out)
  gemm_mfma<1><<<MV_SZ / 128, 512, 0, stream>>>(value, wtv_ws, bv, v_ws);
  // 2) grids + attention weights
  qproj_kernel<<<NQ_SZ / 16, 256, 0, stream>>>(query, refpts, W_off, b_off,
                                               W_attn, b_attn, Wa1, ba1, Wa2,
                                               ba2, grid_ws, aw_ws);
  // 3) bilinear sampling + weighted accumulation
  sample_kernel<<<NQ_SZ, 256, 0, stream>>>(v_ws, grid_ws, aw_ws, acc_ws);
  // 4) out = acc @ Wo + bo  (f32 out)
  gemm_mfma<0><<<NQ_SZ / 128, 512, 0, stream>>>(acc_ws, wto_ws, bo, out);
}

// Round 4
// 203.227 us; speedup vs baseline: 1.7048x; 1.2055x over previous
//
#include <hip/hip_runtime.h>
#include <math.h>

#define B_SZ 4
#define LQ_SZ 2048
#define C_SZ 256
#define NH_SZ 8
#define NL_SZ 4
#define NP_SZ 8
#define HD_SZ 32
#define LV_SZ 21760
#define NQ_SZ (B_SZ * LQ_SZ)   // 8192
#define MV_SZ (B_SZ * LV_SZ)   // 87040

typedef __attribute__((ext_vector_type(8))) short bf16x8;
typedef __attribute__((ext_vector_type(8))) unsigned short ushort8;
typedef __attribute__((ext_vector_type(4))) float f32x4;

__device__ __forceinline__ float bf2f(unsigned short u) {
  union { float f; unsigned v; } x;
  x.v = ((unsigned)u) << 16;
  return x.f;
}
__device__ __forceinline__ unsigned short f2bf(float f) {
  union { float f; unsigned v; } x;
  x.f = f;
  unsigned r = x.v + 0x7fffu + ((x.v >> 16) & 1u);
  return (unsigned short)(r >> 16);
}

// ---------------------------------------------------------------------------
// One-off weight preps (all tiny)
// ---------------------------------------------------------------------------
__global__ void convert_wt(const float* __restrict__ W,
                           unsigned short* __restrict__ Wt) {
  const int n = blockIdx.x, k = threadIdx.x;   // W is (256,256)
  Wt[n * 256 + k] = f2bf(W[k * 256 + n]);
}

// wcat[n][k], n<512: W_off, n<768: W_attn, n<896: Wa1, else 0
__global__ void build_wcat(const float* __restrict__ W_off,
                           const float* __restrict__ W_attn,
                           const float* __restrict__ Wa1,
                           unsigned short* __restrict__ wcat) {
  const int n = blockIdx.x, k = threadIdx.x;
  float v;
  if (n < 512) v = W_off[k * 512 + n];
  else if (n < 768) v = W_attn[k * 256 + (n - 512)];
  else if (n < 896) v = Wa1[k * 128 + (n - 768)];
  else v = 0.f;
  wcat[n * 256 + k] = f2bf(v);
}

__global__ void build_bcat(const float* __restrict__ b_off,
                           const float* __restrict__ b_attn,
                           const float* __restrict__ ba1,
                           float* __restrict__ bcat) {
  const int idx = blockIdx.x * 256 + threadIdx.x;
  float v;
  if (idx < 512) v = b_off[idx];
  else if (idx < 768) v = b_attn[idx - 512];
  else if (idx < 896) v = ba1[idx - 768];
  else v = 0.f;
  bcat[idx] = v;
}

// wa2t[n][k] = bf16(Wa2[k][n]), Wa2 is (128,512)
__global__ void build_wa2t(const float* __restrict__ Wa2,
                           unsigned short* __restrict__ wa2t) {
  const int n = blockIdx.x, k = threadIdx.x;
  wa2t[n * 128 + k] = f2bf(Wa2[k * 512 + n]);
}

// ---------------------------------------------------------------------------
// MFMA GEMM: C[M,n_total] = A[M,K_DIM] @ Wt^T + bias
// Wt pre-transposed bf16: Wt[n][K_DIM]. BM=128, BN=256 (grid.y tiles), BK=32.
// 512 threads = 8 waves (2 row x 4 col), each wave 64x64 = 4x4 fragments.
// ---------------------------------------------------------------------------
#define AS_STRIDE 40  // ushorts per LDS row (80 B -> only free 2-way aliasing)

template <int OUT_BF16, int A_BF16, int K_DIM>
__global__ __launch_bounds__(512, 1) void gemm_mfma(
    const void* __restrict__ Ain, const unsigned short* __restrict__ Wt,
    const float* __restrict__ bias, void* __restrict__ Cout, int n_total) {
  constexpr int KSTEPS = K_DIM / 32;
  __shared__ unsigned short As[2][128 * AS_STRIDE];
  const int tid = threadIdx.x;
  const long bm = (long)blockIdx.x * 128;
  const int bn0 = blockIdx.y * 256;
  const int lane = tid & 63;
  const int wid = tid >> 6;
  const int wr = wid >> 2;         // 0..1
  const int wc = wid & 3;          // 0..3
  const int rowg = (lane >> 4);    // 0..3
  const int rowc = lane & 15;      // 0..15

  const int srow = tid >> 2;       // 0..127
  const int skc = (tid & 3) * 8;   // 0,8,16,24

  f32x4 acc[4][4];
#pragma unroll
  for (int m = 0; m < 4; ++m)
#pragma unroll
    for (int n = 0; n < 4; ++n) acc[m][n] = (f32x4){0.f, 0.f, 0.f, 0.f};

  const float* srcf = (const float*)Ain + (bm + srow) * (long)K_DIM + skc;
  const unsigned short* srcb =
      (const unsigned short*)Ain + (bm + srow) * (long)K_DIM + skc;

  // prologue: stage k-tile 0 into buf 0
  {
    ushort8 u;
    if constexpr (A_BF16) {
      u = *(const ushort8*)srcb;
    } else {
      float4 f0 = *(const float4*)(srcf + 0);
      float4 f1 = *(const float4*)(srcf + 4);
      u[0] = f2bf(f0.x); u[1] = f2bf(f0.y); u[2] = f2bf(f0.z); u[3] = f2bf(f0.w);
      u[4] = f2bf(f1.x); u[5] = f2bf(f1.y); u[6] = f2bf(f1.z); u[7] = f2bf(f1.w);
    }
    *(ushort8*)&As[0][srow * AS_STRIDE + skc] = u;
  }
  __syncthreads();

  int cur = 0;
#pragma unroll
  for (int ks = 0; ks < KSTEPS; ++ks) {
    ushort8 pre;
    if (ks < KSTEPS - 1) {
      if constexpr (A_BF16) {
        pre = *(const ushort8*)(srcb + (ks + 1) * 32);
      } else {
        float4 f0 = *(const float4*)(srcf + (ks + 1) * 32 + 0);
        float4 f1 = *(const float4*)(srcf + (ks + 1) * 32 + 4);
        pre[0] = f2bf(f0.x); pre[1] = f2bf(f0.y);
        pre[2] = f2bf(f0.z); pre[3] = f2bf(f0.w);
        pre[4] = f2bf(f1.x); pre[5] = f2bf(f1.y);
        pre[6] = f2bf(f1.z); pre[7] = f2bf(f1.w);
      }
    }
    bf16x8 bfrag[4];
#pragma unroll
    for (int n = 0; n < 4; ++n) {
      const unsigned short* wp =
          Wt + (long)(bn0 + wc * 64 + n * 16 + rowc) * K_DIM + ks * 32 +
          rowg * 8;
      bfrag[n] = *(const bf16x8*)wp;
    }
    bf16x8 afrag[4];
#pragma unroll
    for (int m = 0; m < 4; ++m) {
      const int r = wr * 64 + m * 16 + rowc;
      afrag[m] = *(const bf16x8*)&As[cur][r * AS_STRIDE + rowg * 8];
    }
#pragma unroll
    for (int m = 0; m < 4; ++m)
#pragma unroll
      for (int n = 0; n < 4; ++n)
        acc[m][n] = __builtin_amdgcn_mfma_f32_16x16x32_bf16(
            afrag[m], bfrag[n], acc[m][n], 0, 0, 0);

    if (ks < KSTEPS - 1) {
      *(ushort8*)&As[cur ^ 1][srow * AS_STRIDE + skc] = pre;
    }
    __syncthreads();
    cur ^= 1;
  }

  // epilogue
#pragma unroll
  for (int m = 0; m < 4; ++m) {
#pragma unroll
    for (int n = 0; n < 4; ++n) {
      const int col = bn0 + wc * 64 + n * 16 + rowc;
      const float bb = bias[col];
#pragma unroll
      for (int j = 0; j < 4; ++j) {
        const long row = bm + wr * 64 + m * 16 + rowg * 4 + j;
        const float val = acc[m][n][j] + bb;
        if (OUT_BF16)
          ((unsigned short*)Cout)[row * n_total + col] = f2bf(val);
        else
          ((float*)Cout)[row * n_total + col] = val;
      }
    }
  }
}

// ---------------------------------------------------------------------------
// hidb = bf16(relu(proj[:, 768:896]))
// ---------------------------------------------------------------------------
__global__ __launch_bounds__(256) void relu_hid(const float* __restrict__ proj,
                                                unsigned short* __restrict__ hidb) {
  const int idx = blockIdx.x * 256 + threadIdx.x;  // < 8192*128
  const int q = idx >> 7, j = idx & 127;
  hidb[idx] = f2bf(fmaxf(proj[(long)q * 1024 + 768 + j], 0.f));
}

// ---------------------------------------------------------------------------
// finalize: grid coords + softmax attention weights.
// One block = 16 queries, 256 threads.
// ---------------------------------------------------------------------------
__global__ __launch_bounds__(256) void finalize_qproj(
    const float* __restrict__ proj, const float* __restrict__ off2,
    const float* __restrict__ refpts, float* __restrict__ grid_out,
    float* __restrict__ aw_out) {
  const int tid = threadIdx.x;
  const long q0 = (long)blockIdx.x * 16;
#pragma unroll 4
  for (int q = 0; q < 16; ++q) {
    const long qi = q0 + q;
    const float* pr = proj + qi * 1024;
    // softmax over 32-sample groups (one head per 32 lanes)
    float logit = pr[512 + tid];
    float m = logit;
#pragma unroll
    for (int mask = 16; mask > 0; mask >>= 1)
      m = fmaxf(m, __shfl_xor(m, mask));
    float e = __expf(logit - m);
    float s = e;
#pragma unroll
    for (int mask = 16; mask > 0; mask >>= 1) s += __shfl_xor(s, mask);
    aw_out[qi * 256 + tid] = e / s;
    // sampling grid
#pragma unroll
    for (int half = 0; half < 2; ++half) {
      const int o = tid + half * 256;
      const float offv = pr[o] + 0.1f * off2[qi * 512 + o];
      const int l = (o >> 4) & 3;
      const int c = o & 1;
      const float rnorm = 1.f / (float)(128 >> l);
      const float ref = refpts[qi * 8 + l * 2 + c];
      grid_out[qi * 512 + o] = (ref + offv * rnorm) * 2.f - 1.f;
    }
  }
}

// ---------------------------------------------------------------------------
// Bilinear sampling + attention-weighted accumulation. v is bf16.
// One block per query; 256 threads = 8 heads x 32 channels.
// ---------------------------------------------------------------------------
__global__ __launch_bounds__(256) void sample_kernel(
    const unsigned short* __restrict__ v, const float* __restrict__ grid,
    const float* __restrict__ aw, float* __restrict__ acc_out) {
  const long qi = blockIdx.x;
  const int b = (int)(qi >> 11);
  const int tid = threadIdx.x;
  const int h = tid >> 5, d = tid & 31;

  __shared__ float gs[512];
  __shared__ float aws[256];
  if (tid < 128) {
    ((float4*)gs)[tid] = ((const float4*)(grid + qi * 512))[tid];
  } else if (tid < 192) {
    ((float4*)aws)[tid - 128] = ((const float4*)(aw + qi * 256))[tid - 128];
  }
  __syncthreads();

  constexpr int starts[4] = {0, 16384, 20480, 21504};
  float acc = 0.f;
  const unsigned short* vb = v + (long)b * LV_SZ * 256 + h * 32 + d;
#pragma unroll
  for (int l = 0; l < 4; ++l) {
    const int HW = 128 >> l;
    const float fHW = (float)HW;
    const unsigned short* vl = vb + (long)starts[l] * 256;
#pragma unroll
    for (int p = 0; p < 8; ++p) {
      const int gidx = h * 64 + l * 16 + p * 2;
      const float gx = gs[gidx], gy = gs[gidx + 1];
      const float w = aws[h * 32 + l * 8 + p];
      const float x = ((gx + 1.f) * fHW - 1.f) * 0.5f;
      const float y = ((gy + 1.f) * fHW - 1.f) * 0.5f;
      const float x0f = floorf(x), y0f = floorf(y);
      const float lx = x - x0f, ly = y - y0f;
      const int ix0 = (int)x0f, iy0 = (int)y0f;
      const int ix1 = ix0 + 1, iy1 = iy0 + 1;
      const float vx0 = (ix0 >= 0 && ix0 < HW) ? 1.f : 0.f;
      const float vx1 = (ix1 >= 0 && ix1 < HW) ? 1.f : 0.f;
      const float vy0 = (iy0 >= 0 && iy0 < HW) ? 1.f : 0.f;
      const float vy1 = (iy1 >= 0 && iy1 < HW) ? 1.f : 0.f;
      const int cx0 = min(max(ix0, 0), HW - 1);
      const int cx1 = min(max(ix1, 0), HW - 1);
      const int cy0 = min(max(iy0, 0), HW - 1);
      const int cy1 = min(max(iy1, 0), HW - 1);
      const float w00 = (1.f - lx) * (1.f - ly) * vx0 * vy0 * w;
      const float w10 = lx * (1.f - ly) * vx1 * vy0 * w;
      const float w01 = (1.f - lx) * ly * vx0 * vy1 * w;
      const float w11 = lx * ly * vx1 * vy1 * w;
      const unsigned short* r0 = vl + (long)(cy0 * HW) * 256;
      const unsigned short* r1 = vl + (long)(cy1 * HW) * 256;
      const float v00 = bf2f(r0[(long)cx0 * 256]);
      const float v10 = bf2f(r0[(long)cx1 * 256]);
      const float v01 = bf2f(r1[(long)cx0 * 256]);
      const float v11 = bf2f(r1[(long)cx1 * 256]);
      acc = fmaf(v00, w00, acc);
      acc = fmaf(v10, w10, acc);
      acc = fmaf(v01, w01, acc);
      acc = fmaf(v11, w11, acc);
    }
  }
  acc_out[qi * 256 + tid] = acc;
}

// ---------------------------------------------------------------------------
extern "C" void kernel_launch(void* const* d_in, const int* in_sizes, int n_in,
                              void* d_out, int out_size, void* d_ws,
                              size_t ws_size, hipStream_t stream) {
  const float* query  = (const float*)d_in[0];
  const float* refpts = (const float*)d_in[1];
  const float* value  = (const float*)d_in[2];
  const float* W_off  = (const float*)d_in[5];
  const float* b_off  = (const float*)d_in[6];
  const float* W_attn = (const float*)d_in[7];
  const float* b_attn = (const float*)d_in[8];
  const float* Wa1    = (const float*)d_in[9];
  const float* ba1    = (const float*)d_in[10];
  const float* Wa2    = (const float*)d_in[11];
  const float* ba2    = (const float*)d_in[12];
  const float* Wv     = (const float*)d_in[13];
  const float* bv     = (const float*)d_in[14];
  const float* Wo     = (const float*)d_in[15];
  const float* bo     = (const float*)d_in[16];
  float* out = (float*)d_out;

  char* ws = (char*)d_ws;
  // layout (total 122,556,416 B):
  unsigned short* v_ws = (unsigned short*)ws;                   // 44,564,480
  float* proj_ws = (float*)(ws + 44564480);                     // 33,554,432
  float* acc_ws  = (float*)(ws + 44564480);        // aliases proj (dead then)
  float* off2_ws = (float*)(ws + 78118912);                     // 16,777,216
  unsigned short* wcat_ws = (unsigned short*)(ws + 78118912);   // aliases off2
  unsigned short* hidb_ws = (unsigned short*)(ws + 94896128);   //  2,097,152
  float* grid_ws = (float*)(ws + 96993280);                     // 16,777,216
  float* aw_ws   = (float*)(ws + 113770496);                    //  8,388,608
  unsigned short* wtv_ws  = (unsigned short*)(ws + 122159104);  //    131,072
  unsigned short* wto_ws  = (unsigned short*)(ws + 122290176);  //    131,072
  unsigned short* wa2t_ws = (unsigned short*)(ws + 122421248);  //    131,072
  float* bcat_ws = (float*)(ws + 122552320);                    //      4,096

  // 0) weight preps
  convert_wt<<<256, 256, 0, stream>>>(Wv, wtv_ws);
  convert_wt<<<256, 256, 0, stream>>>(Wo, wto_ws);
  build_wcat<<<1024, 256, 0, stream>>>(W_off, W_attn, Wa1, wcat_ws);
  build_bcat<<<4, 256, 0, stream>>>(b_off, b_attn, ba1, bcat_ws);
  build_wa2t<<<512, 128, 0, stream>>>(Wa2, wa2t_ws);
  // 1) v = value @ Wv + bv  (bf16 out)
  gemm_mfma<1, 0, 256><<<dim3(MV_SZ / 128, 1), 512, 0, stream>>>(
      value, wtv_ws, bv, v_ws, 256);
  // 2) proj = query @ [W_off|W_attn|Wa1|0] + bcat
  gemm_mfma<0, 0, 256><<<dim3(NQ_SZ / 128, 4), 512, 0, stream>>>(
      query, wcat_ws, bcat_ws, proj_ws, 1024);
  // 3) hidb = bf16(relu(proj[:,768:896]))
  relu_hid<<<NQ_SZ * 128 / 256, 256, 0, stream>>>(proj_ws, hidb_ws);
  // 4) off2 = hidb @ Wa2 + ba2
  gemm_mfma<0, 1, 128><<<dim3(NQ_SZ / 128, 2), 512, 0, stream>>>(
      hidb_ws, wa2t_ws, ba2, off2_ws, 512);
  // 5) grids + attention weights
  finalize_qproj<<<NQ_SZ / 16, 256, 0, stream>>>(proj_ws, off2_ws, refpts,
                                                 grid_ws, aw_ws);
  // 6) bilinear sampling + weighted accumulation
  sample_kernel<<<NQ_SZ, 256, 0, stream>>>(v_ws, grid_ws, aw_ws, acc_ws);
  // 7) out = acc @ Wo + bo
  gemm_mfma<0, 0, 256><<<dim3(NQ_SZ / 128, 1), 512, 0, stream>>>(
      acc_ws, wto_ws, bo, out, 256);
}

// Round 5
// 157.599 us; speedup vs baseline: 2.1984x; 1.2895x over previous
//
#include <hip/hip_runtime.h>
#include <math.h>

#define B_SZ 4
#define LQ_SZ 2048
#define C_SZ 256
#define NH_SZ 8
#define NL_SZ 4
#define NP_SZ 8
#define HD_SZ 32
#define LV_SZ 21760
#define NQ_SZ (B_SZ * LQ_SZ)   // 8192
#define MV_SZ (B_SZ * LV_SZ)   // 87040

typedef __attribute__((ext_vector_type(8))) short bf16x8;
typedef __attribute__((ext_vector_type(8))) unsigned short ushort8;
typedef __attribute__((ext_vector_type(4))) float f32x4;

__device__ __forceinline__ float bf2f(unsigned short u) {
  union { float f; unsigned v; } x;
  x.v = ((unsigned)u) << 16;
  return x.f;
}
__device__ __forceinline__ unsigned short f2bf(float f) {
  union { float f; unsigned v; } x;
  x.f = f;
  unsigned r = x.v + 0x7fffu + ((x.v >> 16) & 1u);
  return (unsigned short)(r >> 16);
}

// ---------------------------------------------------------------------------
// One-off weight preps (all tiny)
// ---------------------------------------------------------------------------
__global__ void convert_wt(const float* __restrict__ W,
                           unsigned short* __restrict__ Wt) {
  const int n = blockIdx.x, k = threadIdx.x;   // W is (256,256)
  Wt[n * 256 + k] = f2bf(W[k * 256 + n]);
}

// wcat[n][k], n<512: W_off, n<768: W_attn, n<896: Wa1, else 0
__global__ void build_wcat(const float* __restrict__ W_off,
                           const float* __restrict__ W_attn,
                           const float* __restrict__ Wa1,
                           unsigned short* __restrict__ wcat) {
  const int n = blockIdx.x, k = threadIdx.x;
  float v;
  if (n < 512) v = W_off[k * 512 + n];
  else if (n < 768) v = W_attn[k * 256 + (n - 512)];
  else if (n < 896) v = Wa1[k * 128 + (n - 768)];
  else v = 0.f;
  wcat[n * 256 + k] = f2bf(v);
}

__global__ void build_bcat(const float* __restrict__ b_off,
                           const float* __restrict__ b_attn,
                           const float* __restrict__ ba1,
                           float* __restrict__ bcat) {
  const int idx = blockIdx.x * 256 + threadIdx.x;
  float v;
  if (idx < 512) v = b_off[idx];
  else if (idx < 768) v = b_attn[idx - 512];
  else if (idx < 896) v = ba1[idx - 768];
  else v = 0.f;
  bcat[idx] = v;
}

// wa2t[n][k] = bf16(Wa2[k][n]), Wa2 is (128,512)
__global__ void build_wa2t(const float* __restrict__ Wa2,
                           unsigned short* __restrict__ wa2t) {
  const int n = blockIdx.x, k = threadIdx.x;
  wa2t[n * 128 + k] = f2bf(Wa2[k * 512 + n]);
}

// ---------------------------------------------------------------------------
// MFMA GEMM: C[M,n_total] = A[M,K_DIM] @ Wt^T + bias
// Wt pre-transposed bf16: Wt[n][K_DIM]. BM=128, BN=256 (grid.y tiles), BK=32.
// 512 threads = 8 waves (2 row x 4 col), each wave 64x64 = 4x4 fragments.
// ---------------------------------------------------------------------------
#define AS_STRIDE 40  // ushorts per LDS row (80 B -> only free 2-way aliasing)

template <int OUT_BF16, int A_BF16, int K_DIM>
__global__ __launch_bounds__(512, 1) void gemm_mfma(
    const void* __restrict__ Ain, const unsigned short* __restrict__ Wt,
    const float* __restrict__ bias, void* __restrict__ Cout, int n_total) {
  constexpr int KSTEPS = K_DIM / 32;
  __shared__ unsigned short As[2][128 * AS_STRIDE];
  const int tid = threadIdx.x;
  const long bm = (long)blockIdx.x * 128;
  const int bn0 = blockIdx.y * 256;
  const int lane = tid & 63;
  const int wid = tid >> 6;
  const int wr = wid >> 2;         // 0..1
  const int wc = wid & 3;          // 0..3
  const int rowg = (lane >> 4);    // 0..3
  const int rowc = lane & 15;      // 0..15

  const int srow = tid >> 2;       // 0..127
  const int skc = (tid & 3) * 8;   // 0,8,16,24

  f32x4 acc[4][4];
#pragma unroll
  for (int m = 0; m < 4; ++m)
#pragma unroll
    for (int n = 0; n < 4; ++n) acc[m][n] = (f32x4){0.f, 0.f, 0.f, 0.f};

  const float* srcf = (const float*)Ain + (bm + srow) * (long)K_DIM + skc;
  const unsigned short* srcb =
      (const unsigned short*)Ain + (bm + srow) * (long)K_DIM + skc;

  // prologue: stage k-tile 0 into buf 0
  {
    ushort8 u;
    if constexpr (A_BF16) {
      u = *(const ushort8*)srcb;
    } else {
      float4 f0 = *(const float4*)(srcf + 0);
      float4 f1 = *(const float4*)(srcf + 4);
      u[0] = f2bf(f0.x); u[1] = f2bf(f0.y); u[2] = f2bf(f0.z); u[3] = f2bf(f0.w);
      u[4] = f2bf(f1.x); u[5] = f2bf(f1.y); u[6] = f2bf(f1.z); u[7] = f2bf(f1.w);
    }
    *(ushort8*)&As[0][srow * AS_STRIDE + skc] = u;
  }
  __syncthreads();

  int cur = 0;
#pragma unroll
  for (int ks = 0; ks < KSTEPS; ++ks) {
    ushort8 pre;
    if (ks < KSTEPS - 1) {
      if constexpr (A_BF16) {
        pre = *(const ushort8*)(srcb + (ks + 1) * 32);
      } else {
        float4 f0 = *(const float4*)(srcf + (ks + 1) * 32 + 0);
        float4 f1 = *(const float4*)(srcf + (ks + 1) * 32 + 4);
        pre[0] = f2bf(f0.x); pre[1] = f2bf(f0.y);
        pre[2] = f2bf(f0.z); pre[3] = f2bf(f0.w);
        pre[4] = f2bf(f1.x); pre[5] = f2bf(f1.y);
        pre[6] = f2bf(f1.z); pre[7] = f2bf(f1.w);
      }
    }
    bf16x8 bfrag[4];
#pragma unroll
    for (int n = 0; n < 4; ++n) {
      const unsigned short* wp =
          Wt + (long)(bn0 + wc * 64 + n * 16 + rowc) * K_DIM + ks * 32 +
          rowg * 8;
      bfrag[n] = *(const bf16x8*)wp;
    }
    bf16x8 afrag[4];
#pragma unroll
    for (int m = 0; m < 4; ++m) {
      const int r = wr * 64 + m * 16 + rowc;
      afrag[m] = *(const bf16x8*)&As[cur][r * AS_STRIDE + rowg * 8];
    }
#pragma unroll
    for (int m = 0; m < 4; ++m)
#pragma unroll
      for (int n = 0; n < 4; ++n)
        acc[m][n] = __builtin_amdgcn_mfma_f32_16x16x32_bf16(
            afrag[m], bfrag[n], acc[m][n], 0, 0, 0);

    if (ks < KSTEPS - 1) {
      *(ushort8*)&As[cur ^ 1][srow * AS_STRIDE + skc] = pre;
    }
    __syncthreads();
    cur ^= 1;
  }

  // epilogue
#pragma unroll
  for (int m = 0; m < 4; ++m) {
#pragma unroll
    for (int n = 0; n < 4; ++n) {
      const int col = bn0 + wc * 64 + n * 16 + rowc;
      const float bb = bias[col];
#pragma unroll
      for (int j = 0; j < 4; ++j) {
        const long row = bm + wr * 64 + m * 16 + rowg * 4 + j;
        const float val = acc[m][n][j] + bb;
        if (OUT_BF16)
          ((unsigned short*)Cout)[row * n_total + col] = f2bf(val);
        else
          ((float*)Cout)[row * n_total + col] = val;
      }
    }
  }
}

// ---------------------------------------------------------------------------
// hidb = bf16(relu(proj[:, 768:896]))
// ---------------------------------------------------------------------------
__global__ __launch_bounds__(256) void relu_hid(const float* __restrict__ proj,
                                                unsigned short* __restrict__ hidb) {
  const int idx = blockIdx.x * 256 + threadIdx.x;  // < 8192*128
  const int q = idx >> 7, j = idx & 127;
  hidb[idx] = f2bf(fmaxf(proj[(long)q * 1024 + 768 + j], 0.f));
}

// ---------------------------------------------------------------------------
// finalize: grid coords + softmax attention weights.
// One block = 16 queries, 256 threads.
// ---------------------------------------------------------------------------
__global__ __launch_bounds__(256) void finalize_qproj(
    const float* __restrict__ proj, const float* __restrict__ off2,
    const float* __restrict__ refpts, float* __restrict__ grid_out,
    float* __restrict__ aw_out) {
  const int tid = threadIdx.x;
  const long q0 = (long)blockIdx.x * 16;
#pragma unroll 4
  for (int q = 0; q < 16; ++q) {
    const long qi = q0 + q;
    const float* pr = proj + qi * 1024;
    // softmax over 32-sample groups (one head per 32 lanes)
    float logit = pr[512 + tid];
    float m = logit;
#pragma unroll
    for (int mask = 16; mask > 0; mask >>= 1)
      m = fmaxf(m, __shfl_xor(m, mask));
    float e = __expf(logit - m);
    float s = e;
#pragma unroll
    for (int mask = 16; mask > 0; mask >>= 1) s += __shfl_xor(s, mask);
    aw_out[qi * 256 + tid] = e / s;
    // sampling grid
#pragma unroll
    for (int half = 0; half < 2; ++half) {
      const int o = tid + half * 256;
      const float offv = pr[o] + 0.1f * off2[qi * 512 + o];
      const int l = (o >> 4) & 3;
      const int c = o & 1;
      const float rnorm = 1.f / (float)(128 >> l);
      const float ref = refpts[qi * 8 + l * 2 + c];
      grid_out[qi * 512 + o] = (ref + offv * rnorm) * 2.f - 1.f;
    }
  }
}

// ---------------------------------------------------------------------------
// Bilinear sampling + attention-weighted accumulation. v is bf16.
// Block = 2 queries, 256 threads.
// Phase 1: 512 samples -> corner byte-offsets + fused weights in LDS.
// Phase 2: thread = (query, head, channel-pair); 32 samples x 4 corners,
//          ushort2 loads (2 channels), broadcast LDS reads.
// ---------------------------------------------------------------------------
__global__ __launch_bounds__(256) void sample_kernel(
    const unsigned short* __restrict__ v, const float* __restrict__ grid,
    const float* __restrict__ aw, float* __restrict__ acc_out) {
  __shared__ int4 sidx[512];
  __shared__ float4 sw[512];
  const int tid = threadIdx.x;
  const long q0 = (long)blockIdx.x * 2;
  const int b = (int)(q0 >> 11);
  constexpr int starts[4] = {0, 16384, 20480, 21504};

  // ---- phase 1: per-sample corner offsets + weights ----
#pragma unroll
  for (int ss = 0; ss < 2; ++ss) {
    const int s = tid + ss * 256;
    const int qq = s >> 8, j = s & 255;       // j = h*32 + l*8 + p
    const int l = (j >> 3) & 3;
    const int HW = 128 >> l;
    const float fHW = (float)HW;
    const float2 g = *(const float2*)(grid + (q0 + qq) * 512 + 2 * j);
    const float w = aw[(q0 + qq) * 256 + j];
    const float x = ((g.x + 1.f) * fHW - 1.f) * 0.5f;
    const float y = ((g.y + 1.f) * fHW - 1.f) * 0.5f;
    const float x0f = floorf(x), y0f = floorf(y);
    const float lx = x - x0f, ly = y - y0f;
    const int ix0 = (int)x0f, iy0 = (int)y0f;
    const int ix1 = ix0 + 1, iy1 = iy0 + 1;
    const float vx0 = (ix0 >= 0 && ix0 < HW) ? 1.f : 0.f;
    const float vx1 = (ix1 >= 0 && ix1 < HW) ? 1.f : 0.f;
    const float vy0 = (iy0 >= 0 && iy0 < HW) ? 1.f : 0.f;
    const float vy1 = (iy1 >= 0 && iy1 < HW) ? 1.f : 0.f;
    const int cx0 = min(max(ix0, 0), HW - 1);
    const int cx1 = min(max(ix1, 0), HW - 1);
    const int cy0 = min(max(iy0, 0), HW - 1);
    const int cy1 = min(max(iy1, 0), HW - 1);
    const int base = starts[l];
    int4 o;  // byte offsets into v (256 ch * 2 B per location)
    o.x = (base + cy0 * HW + cx0) * 512;
    o.y = (base + cy0 * HW + cx1) * 512;
    o.z = (base + cy1 * HW + cx0) * 512;
    o.w = (base + cy1 * HW + cx1) * 512;
    sidx[s] = o;
    float4 wv;
    wv.x = (1.f - lx) * (1.f - ly) * vx0 * vy0 * w;
    wv.y = lx * (1.f - ly) * vx1 * vy0 * w;
    wv.z = (1.f - lx) * ly * vx0 * vy1 * w;
    wv.w = lx * ly * vx1 * vy1 * w;
    sw[s] = wv;
  }
  __syncthreads();

  // ---- phase 2: gather + weighted accumulate, 2 channels/thread ----
  const int qq = tid >> 7, h = (tid >> 4) & 7, dp = tid & 15;
  const char* vb =
      (const char*)v + ((long)b * LV_SZ * 256 + h * 32 + dp * 2) * 2;
  const int sbase = qq * 256 + h * 32;
  float acc0 = 0.f, acc1 = 0.f;
#pragma unroll 8
  for (int j = 0; j < 32; ++j) {
    const int4 o = sidx[sbase + j];
    const float4 w = sw[sbase + j];
    const ushort2 u0 = *(const ushort2*)(vb + o.x);
    const ushort2 u1 = *(const ushort2*)(vb + o.y);
    const ushort2 u2 = *(const ushort2*)(vb + o.z);
    const ushort2 u3 = *(const ushort2*)(vb + o.w);
    acc0 = fmaf(bf2f(u0.x), w.x, acc0);
    acc1 = fmaf(bf2f(u0.y), w.x, acc1);
    acc0 = fmaf(bf2f(u1.x), w.y, acc0);
    acc1 = fmaf(bf2f(u1.y), w.y, acc1);
    acc0 = fmaf(bf2f(u2.x), w.z, acc0);
    acc1 = fmaf(bf2f(u2.y), w.z, acc1);
    acc0 = fmaf(bf2f(u3.x), w.w, acc0);
    acc1 = fmaf(bf2f(u3.y), w.w, acc1);
  }
  float2 res = {acc0, acc1};
  *(float2*)(acc_out + (q0 + qq) * 256 + h * 32 + dp * 2) = res;
}

// ---------------------------------------------------------------------------
extern "C" void kernel_launch(void* const* d_in, const int* in_sizes, int n_in,
                              void* d_out, int out_size, void* d_ws,
                              size_t ws_size, hipStream_t stream) {
  const float* query  = (const float*)d_in[0];
  const float* refpts = (const float*)d_in[1];
  const float* value  = (const float*)d_in[2];
  const float* W_off  = (const float*)d_in[5];
  const float* b_off  = (const float*)d_in[6];
  const float* W_attn = (const float*)d_in[7];
  const float* b_attn = (const float*)d_in[8];
  const float* Wa1    = (const float*)d_in[9];
  const float* ba1    = (const float*)d_in[10];
  const float* Wa2    = (const float*)d_in[11];
  const float* ba2    = (const float*)d_in[12];
  const float* Wv     = (const float*)d_in[13];
  const float* bv     = (const float*)d_in[14];
  const float* Wo     = (const float*)d_in[15];
  const float* bo     = (const float*)d_in[16];
  float* out = (float*)d_out;

  char* ws = (char*)d_ws;
  // layout (total 122,556,416 B):
  unsigned short* v_ws = (unsigned short*)ws;                   // 44,564,480
  float* proj_ws = (float*)(ws + 44564480);                     // 33,554,432
  float* acc_ws  = (float*)(ws + 44564480);        // aliases proj (dead then)
  float* off2_ws = (float*)(ws + 78118912);                     // 16,777,216
  unsigned short* wcat_ws = (unsigned short*)(ws + 78118912);   // aliases off2
  unsigned short* hidb_ws = (unsigned short*)(ws + 94896128);   //  2,097,152
  float* grid_ws = (float*)(ws + 96993280);                     // 16,777,216
  float* aw_ws   = (float*)(ws + 113770496);                    //  8,388,608
  unsigned short* wtv_ws  = (unsigned short*)(ws + 122159104);  //    131,072
  unsigned short* wto_ws  = (unsigned short*)(ws + 122290176);  //    131,072
  unsigned short* wa2t_ws = (unsigned short*)(ws + 122421248);  //    131,072
  float* bcat_ws = (float*)(ws + 122552320);                    //      4,096

  // 0) weight preps
  convert_wt<<<256, 256, 0, stream>>>(Wv, wtv_ws);
  convert_wt<<<256, 256, 0, stream>>>(Wo, wto_ws);
  build_wcat<<<1024, 256, 0, stream>>>(W_off, W_attn, Wa1, wcat_ws);
  build_bcat<<<4, 256, 0, stream>>>(b_off, b_attn, ba1, bcat_ws);
  build_wa2t<<<512, 128, 0, stream>>>(Wa2, wa2t_ws);
  // 1) v = value @ Wv + bv  (bf16 out)
  gemm_mfma<1, 0, 256><<<dim3(MV_SZ / 128, 1), 512, 0, stream>>>(
      value, wtv_ws, bv, v_ws, 256);
  // 2) proj = query @ [W_off|W_attn|Wa1|0] + bcat
  gemm_mfma<0, 0, 256><<<dim3(NQ_SZ / 128, 4), 512, 0, stream>>>(
      query, wcat_ws, bcat_ws, proj_ws, 1024);
  // 3) hidb = bf16(relu(proj[:,768:896]))
  relu_hid<<<NQ_SZ * 128 / 256, 256, 0, stream>>>(proj_ws, hidb_ws);
  // 4) off2 = hidb @ Wa2 + ba2
  gemm_mfma<0, 1, 128><<<dim3(NQ_SZ / 128, 2), 512, 0, stream>>>(
      hidb_ws, wa2t_ws, ba2, off2_ws, 512);
  // 5) grids + attention weights
  finalize_qproj<<<NQ_SZ / 16, 256, 0, stream>>>(proj_ws, off2_ws, refpts,
                                                 grid_ws, aw_ws);
  // 6) bilinear sampling + weighted accumulation
  sample_kernel<<<NQ_SZ / 2, 256, 0, stream>>>(v_ws, grid_ws, aw_ws, acc_ws);
  // 7) out = acc @ Wo + bo
  gemm_mfma<0, 0, 256><<<dim3(NQ_SZ / 128, 1), 512, 0, stream>>>(
      acc_ws, wto_ws, bo, out, 256);
}